// Round 2
// baseline (9889.662 us; speedup 1.0000x reference)
//
#include <hip/hip_runtime.h>
#include <hip/hip_bf16.h>
#include <stdint.h>

typedef unsigned short u16;

#define B_SZ   4096
#define N_TOT  500
#define IN_CH  8
#define NS     77
#define NE     400
#define L1_OUT 1024
#define L2_OUT 218

// ---------------- bf16 helpers ----------------
__device__ inline u16 f2b(float f) {
  union { float f; uint32_t u; } v; v.f = f;
  uint32_t r = v.u + 0x7FFFu + ((v.u >> 16) & 1u);
  return (u16)(r >> 16);
}
__device__ inline float b2f(u16 h) {
  union { uint32_t u; float f; } v; v.u = ((uint32_t)h) << 16; return v.f;
}
__device__ inline void unpack8(uint4 r, float* a) {
  a[0]=b2f((u16)(r.x & 0xffff)); a[1]=b2f((u16)(r.x >> 16));
  a[2]=b2f((u16)(r.y & 0xffff)); a[3]=b2f((u16)(r.y >> 16));
  a[4]=b2f((u16)(r.z & 0xffff)); a[5]=b2f((u16)(r.z >> 16));
  a[6]=b2f((u16)(r.w & 0xffff)); a[7]=b2f((u16)(r.w >> 16));
}

// ---------------- setup: CSR of incoming valid edges (deterministic) ----------------
__global__ void k_setup(const int* __restrict__ ei, int* __restrict__ coff,
                        int* __restrict__ csrc, float* __restrict__ inv) {
  if (threadIdx.x != 0 || blockIdx.x != 0) return;
  int cnt[NS], cur[NS];
  for (int i = 0; i < NS; ++i) cnt[i] = 0;
  const int* src = ei; const int* dst = ei + NE;
  for (int e = 0; e < NE; ++e) if (src[e] != dst[e]) cnt[dst[e]]++;
  int acc = 0;
  for (int i = 0; i < NS; ++i) {
    coff[i] = acc; cur[i] = acc; acc += cnt[i];
    inv[i] = 1.0f / (float)(cnt[i] + 1);
  }
  coff[NS] = acc;
  for (int e = 0; e < NE; ++e) if (src[e] != dst[e]) csrc[cur[dst[e]]++] = src[e];
}

// ---------------- gather: xt[r,c] = x[b0+r/77, nid[r%77], c] (bf16 out) ----------------
__global__ void k_gather(const float* __restrict__ x, const int* __restrict__ nid,
                         u16* __restrict__ xt, int nrows) {
  int row = blockIdx.x * 256 + threadIdx.x;
  if (row >= nrows) return;
  int b = row / NS, i = row - b * NS;
  const float* p = x + ((size_t)b * N_TOT + nid[i]) * IN_CH;
  float4 v0 = *(const float4*)p;
  float4 v1 = *(const float4*)(p + 4);
  ushort4 o0, o1;
  o0.x = f2b(v0.x); o0.y = f2b(v0.y); o0.z = f2b(v0.z); o0.w = f2b(v0.w);
  o1.x = f2b(v1.x); o1.y = f2b(v1.y); o1.z = f2b(v1.z); o1.w = f2b(v1.w);
  ushort4* q = (ushort4*)(xt + (size_t)row * IN_CH);
  q[0] = o0; q[1] = o1;
}

// ---------------- aggregation: ag = (self + sum_in) * inv, one block per batch elem ----------------
// LDS stages bf16 (max 77*256*2 = 39,424 B for C=256) -> safe under any LDS limit.
template<int C>
__global__ void k_aggr(const u16* __restrict__ h, u16* __restrict__ ag,
                       const int* __restrict__ coff, const int* __restrict__ csrc,
                       const float* __restrict__ inv) {
  __shared__ u16 sh[NS * C];
  __shared__ int soff[NS + 1];
  __shared__ int ssrc[NE];
  __shared__ float sinv[NS];
  const int b = blockIdx.x, t = threadIdx.x;
  const ushort4* hb4 = (const ushort4*)(h + (size_t)b * NS * C);
  ushort4* sh4 = (ushort4*)sh;
  for (int i4 = t; i4 < NS * C / 4; i4 += 256) sh4[i4] = hb4[i4];
  for (int i = t; i < NS + 1; i += 256) soff[i] = coff[i];
  for (int i = t; i < NE; i += 256) ssrc[i] = csrc[i];
  for (int i = t; i < NS; i += 256) sinv[i] = inv[i];
  __syncthreads();
  ushort4* ab4 = (ushort4*)(ag + (size_t)b * NS * C);
  for (int i4 = t; i4 < NS * C / 4; i4 += 256) {
    int i = i4 / (C / 4);
    int c0 = (i4 - i * (C / 4)) * 4;
    ushort4 sv = sh4[i4];
    float s0 = b2f(sv.x), s1 = b2f(sv.y), s2 = b2f(sv.z), s3 = b2f(sv.w);
    int e0 = soff[i], e1 = soff[i + 1];
    for (int e = e0; e < e1; ++e) {
      const u16* np = &sh[ssrc[e] * C + c0];
      ushort4 nv = *(const ushort4*)np;
      s0 += b2f(nv.x); s1 += b2f(nv.y); s2 += b2f(nv.z); s3 += b2f(nv.w);
    }
    float iv = sinv[i];
    ushort4 o; o.x = f2b(s0 * iv); o.y = f2b(s1 * iv); o.z = f2b(s2 * iv); o.w = f2b(s3 * iv);
    ab4[i4] = o;
  }
}

// ---------------- row L2-norm + relu, in place, wave per row ----------------
template<int C>
__global__ void k_normrelu(u16* __restrict__ h) {
  const int row = blockIdx.x * 4 + (threadIdx.x >> 6);
  const int lane = threadIdx.x & 63;
  constexpr int PER = C / 64;           // 1, 4, 8
  u16* hr = h + (size_t)row * C;
  float v[PER];
  if constexpr (PER == 1) {
    v[0] = b2f(hr[lane]);
  } else if constexpr (PER == 4) {
    ushort4 r = *(const ushort4*)(hr + lane * 4);
    v[0]=b2f(r.x); v[1]=b2f(r.y); v[2]=b2f(r.z); v[3]=b2f(r.w);
  } else {
    uint4 r = *(const uint4*)(hr + lane * 8);
    unpack8(r, v);
  }
  float ss = 0.f;
  #pragma unroll
  for (int j = 0; j < PER; ++j) ss += v[j] * v[j];
  #pragma unroll
  for (int d = 1; d < 64; d <<= 1) ss += __shfl_xor(ss, d);
  float rn = 1.0f / fmaxf(sqrtf(ss), 1e-12f);
  #pragma unroll
  for (int j = 0; j < PER; ++j) v[j] = fmaxf(v[j] * rn, 0.f);
  if constexpr (PER == 1) {
    hr[lane] = f2b(v[0]);
  } else if constexpr (PER == 4) {
    ushort4 o; o.x=f2b(v[0]); o.y=f2b(v[1]); o.z=f2b(v[2]); o.w=f2b(v[3]);
    *(ushort4*)(hr + lane * 4) = o;
  } else {
    ushort4 o0, o1;
    o0.x=f2b(v[0]); o0.y=f2b(v[1]); o0.z=f2b(v[2]); o0.w=f2b(v[3]);
    o1.x=f2b(v[4]); o1.y=f2b(v[5]); o1.z=f2b(v[6]); o1.w=f2b(v[7]);
    ushort4* q = (ushort4*)(hr + lane * 8); q[0]=o0; q[1]=o1;
  }
}

// ---------------- tiled GEMM: C[M,N] = act( [A|A2] * W + bias ) ----------------
// BM=128, BN=64, BK=16; 256 threads, 8x4 acc/thread. grid = (M/128)*ntiles.
template<bool ABF16, int CIN, bool RELU, bool OBF16, bool NGUARD>
__global__ __launch_bounds__(256)
void k_gemm(const void* __restrict__ Av, const void* __restrict__ A2v,
            const float* __restrict__ W, const float* __restrict__ bias,
            void* __restrict__ Cv, int N, int K, int ntiles) {
  __shared__ float As[128][20];
  __shared__ float Bs[16][64];
  const int t = threadIdx.x;
  const int bx = blockIdx.x;
  const int mt = bx / ntiles, nt = bx - mt * ntiles;
  const int row0 = mt * 128, col0 = nt * 64;
  const int tr = t >> 4, tc = t & 15;
  const int arow = t >> 1, acol = (t & 1) * 8;
  const int brow = t >> 4, bcol = (t & 15) * 4;

  float acc[8][4];
  #pragma unroll
  for (int r = 0; r < 8; ++r)
    #pragma unroll
    for (int c = 0; c < 4; ++c) acc[r][c] = 0.f;

  for (int k0 = 0; k0 < K; k0 += 16) {
    {
      int gk = k0 + acol;
      const void* base; int koff, lda;
      if constexpr (CIN > 0) {
        lda = CIN;
        if (gk < CIN) { base = Av; koff = gk; } else { base = A2v; koff = gk - CIN; }
      } else { base = Av; koff = gk; lda = K; }
      float av[8];
      if constexpr (ABF16) {
        const u16* p = (const u16*)base + (size_t)(row0 + arow) * lda + koff;
        uint4 raw = *(const uint4*)p;
        unpack8(raw, av);
      } else {
        const float* p = (const float*)base + (size_t)(row0 + arow) * lda + koff;
        float4 u = *(const float4*)p; float4 w = *(const float4*)(p + 4);
        av[0]=u.x; av[1]=u.y; av[2]=u.z; av[3]=u.w;
        av[4]=w.x; av[5]=w.y; av[6]=w.z; av[7]=w.w;
      }
      *(float4*)&As[arow][acol]     = make_float4(av[0],av[1],av[2],av[3]);
      *(float4*)&As[arow][acol + 4] = make_float4(av[4],av[5],av[6],av[7]);
    }
    {
      int gk = k0 + brow, gn = col0 + bcol;
      const float* wp = W + (size_t)gk * N + gn;
      if constexpr (!NGUARD) {
        *(float4*)&Bs[brow][bcol] = *(const float4*)wp;
      } else {
        #pragma unroll
        for (int j = 0; j < 4; ++j) Bs[brow][bcol + j] = (gn + j < N) ? wp[j] : 0.f;
      }
    }
    __syncthreads();
    #pragma unroll
    for (int kk = 0; kk < 16; kk += 4) {
      float4 b0 = *(float4*)&Bs[kk + 0][tc * 4];
      float4 b1 = *(float4*)&Bs[kk + 1][tc * 4];
      float4 b2 = *(float4*)&Bs[kk + 2][tc * 4];
      float4 b3 = *(float4*)&Bs[kk + 3][tc * 4];
      #pragma unroll
      for (int r = 0; r < 8; ++r) {
        float4 a = *(float4*)&As[tr + 16 * r][kk];
        acc[r][0] += a.x*b0.x; acc[r][1] += a.x*b0.y; acc[r][2] += a.x*b0.z; acc[r][3] += a.x*b0.w;
        acc[r][0] += a.y*b1.x; acc[r][1] += a.y*b1.y; acc[r][2] += a.y*b1.z; acc[r][3] += a.y*b1.w;
        acc[r][0] += a.z*b2.x; acc[r][1] += a.z*b2.y; acc[r][2] += a.z*b2.z; acc[r][3] += a.z*b2.w;
        acc[r][0] += a.w*b3.x; acc[r][1] += a.w*b3.y; acc[r][2] += a.w*b3.z; acc[r][3] += a.w*b3.w;
      }
    }
    __syncthreads();
  }
  float bv[4];
  #pragma unroll
  for (int c = 0; c < 4; ++c) {
    int gn = col0 + tc * 4 + c;
    bv[c] = (!NGUARD || gn < N) ? bias[gn] : 0.f;
  }
  #pragma unroll
  for (int r = 0; r < 8; ++r) {
    int gr = row0 + tr + 16 * r;
    float v[4];
    #pragma unroll
    for (int c = 0; c < 4; ++c) {
      v[c] = acc[r][c] + bv[c];
      if constexpr (RELU) v[c] = fmaxf(v[c], 0.f);
    }
    if constexpr (OBF16) {
      u16* cp = (u16*)Cv + (size_t)gr * N + col0 + tc * 4;
      ushort4 o; o.x=f2b(v[0]); o.y=f2b(v[1]); o.z=f2b(v[2]); o.w=f2b(v[3]);
      *(ushort4*)cp = o;
    } else {
      float* cp = (float*)Cv + (size_t)gr * N + col0 + tc * 4;
      if constexpr (!NGUARD) {
        *(float4*)cp = make_float4(v[0], v[1], v[2], v[3]);
      } else {
        #pragma unroll
        for (int c = 0; c < 4; ++c)
          if (col0 + tc * 4 + c < N) cp[c] = v[c];
      }
    }
  }
}

// ---------------- final 218 -> 2 ----------------
__global__ void k_l3(const float* __restrict__ y2, const float* __restrict__ w,
                     const float* __restrict__ b, float* __restrict__ out, int nrows) {
  int idx = blockIdx.x * 256 + threadIdx.x;
  if (idx >= nrows * 2) return;
  int o = idx & 1, row = idx >> 1;
  const float* yr = y2 + (size_t)row * L2_OUT;
  float s = b[o];
  for (int k = 0; k < L2_OUT; ++k) s += yr[k] * w[k * 2 + o];
  out[idx] = s;
}

extern "C" void kernel_launch(void* const* d_in, const int* in_sizes, int n_in,
                              void* d_out, int out_size, void* d_ws, size_t ws_size,
                              hipStream_t stream) {
  const float* x   = (const float*)d_in[0];
  const int*   nid = (const int*)d_in[1];
  const int*   ei  = (const int*)d_in[2];
  const float* W1  = (const float*)d_in[3];  const float* b1 = (const float*)d_in[4];
  const float* W2  = (const float*)d_in[5];  const float* b2 = (const float*)d_in[6];
  const float* W3  = (const float*)d_in[7];  const float* b3 = (const float*)d_in[8];
  const float* L1w = (const float*)d_in[9];  const float* L1b = (const float*)d_in[10];
  const float* L2w = (const float*)d_in[11]; const float* L2b = (const float*)d_in[12];
  const float* L3w = (const float*)d_in[13]; const float* L3b = (const float*)d_in[14];
  float* out = (float*)d_out;

  // ---- adaptive batch-chunk size: per-chunk ws = Bc*157,696 B (3-region overlay) + 64KB meta
  int Bc = 4096;
  while (Bc > 128 && (size_t)Bc * 157696 + 65536 > ws_size) Bc >>= 1;

  char* ws = (char*)d_ws;
  size_t R1 = (size_t)Bc * 39424;   // h2 (bf16 Bc*77*256) -> y1 (f32 Bc*1024)
  size_t R2 = (size_t)Bc * 39424;   // h1 (bf16 Bc*77*64) -> ag2 -> y2 (f32 Bc*218)
  size_t R3 = (size_t)Bc * 78848;   // xt0+ag0 -> ag1 -> h3 (bf16 Bc*77*512)
  char* r1 = ws;
  char* r2 = ws + R1;
  char* r3 = ws + R1 + R2;
  int*   coff = (int*)(ws + R1 + R2 + R3);
  int*   csrc = coff + 80;
  float* invc = (float*)(csrc + 400);

  k_setup<<<1, 64, 0, stream>>>(ei, coff, csrc, invc);

  for (int b0 = 0; b0 < B_SZ; b0 += Bc) {
    const int nb = Bc;                 // B_SZ divisible by all Bc choices
    const int rows = nb * NS;          // multiple of 128 (nb multiple of 128)
    u16* xt0 = (u16*)r3;
    u16* ag0 = (u16*)(r3 + (size_t)nb * 1232);
    u16* h1  = (u16*)r2;
    u16* ag1 = (u16*)r3;
    u16* h2  = (u16*)r1;
    u16* ag2 = (u16*)r2;
    u16* h3  = (u16*)r3;
    float* y1c = (float*)r1;
    float* y2c = (float*)r2;
    const float* xb = x + (size_t)b0 * N_TOT * IN_CH;

    k_gather<<<(rows + 255) / 256, 256, 0, stream>>>(xb, nid, xt0, rows);

    // conv1: 8 -> 64
    k_aggr<8><<<nb, 256, 0, stream>>>(xt0, ag0, coff, csrc, invc);
    k_gemm<true, 8, false, true, false><<<(rows / 128) * 1, 256, 0, stream>>>(
        xt0, ag0, W1, b1, h1, 64, 16, 1);
    k_normrelu<64><<<rows / 4, 256, 0, stream>>>(h1);

    // conv2: 64 -> 256
    k_aggr<64><<<nb, 256, 0, stream>>>(h1, ag1, coff, csrc, invc);
    k_gemm<true, 64, false, true, false><<<(rows / 128) * 4, 256, 0, stream>>>(
        h1, ag1, W2, b2, h2, 256, 128, 4);
    k_normrelu<256><<<rows / 4, 256, 0, stream>>>(h2);

    // conv3: 256 -> 512
    k_aggr<256><<<nb, 256, 0, stream>>>(h2, ag2, coff, csrc, invc);
    k_gemm<true, 256, false, true, false><<<(rows / 128) * 8, 256, 0, stream>>>(
        h2, ag2, W3, b3, h3, 512, 512, 8);
    k_normrelu<512><<<rows / 4, 256, 0, stream>>>(h3);

    // L1: (nb x 39424) @ (39424 x 1024), relu
    k_gemm<true, 0, true, false, false><<<(nb / 128) * 16, 256, 0, stream>>>(
        h3, nullptr, L1w, L1b, y1c, 1024, 39424, 16);
    // L2: (nb x 1024) @ (1024 x 218), relu (N guarded)
    k_gemm<false, 0, true, false, true><<<(nb / 128) * 4, 256, 0, stream>>>(
        y1c, nullptr, L2w, L2b, y2c, 218, 1024, 4);
    // L3: (nb x 218) @ (218 x 2)
    k_l3<<<(nb * 2 + 255) / 256, 256, 0, stream>>>(y2c, L3w, L3b, out + (size_t)b0 * 2, nb);
  }
}

// Round 3
// 1787.965 us; speedup vs baseline: 5.5312x; 5.5312x over previous
//
#include <hip/hip_runtime.h>
#include <hip/hip_bf16.h>
#include <stdint.h>

typedef unsigned short u16;
typedef __attribute__((ext_vector_type(8))) short bf16x8_t;
typedef __attribute__((ext_vector_type(4))) float f32x4_t;

#define B_SZ   4096
#define N_TOT  500
#define IN_CH  8
#define NS     77
#define NE     400
#define L1_OUT 1024
#define L2_OUT 218

#define AS1C(p) ((const __attribute__((address_space(1))) void*)(p))
#define AS3(p)  ((__attribute__((address_space(3))) void*)(p))

// ---------------- bf16 helpers ----------------
__device__ inline u16 f2b(float f) {
  union { float f; uint32_t u; } v; v.f = f;
  uint32_t r = v.u + 0x7FFFu + ((v.u >> 16) & 1u);
  return (u16)(r >> 16);
}
__device__ inline float b2f(u16 h) {
  union { uint32_t u; float f; } v; v.u = ((uint32_t)h) << 16; return v.f;
}
__device__ inline void unpack8(uint4 r, float* a) {
  a[0]=b2f((u16)(r.x & 0xffff)); a[1]=b2f((u16)(r.x >> 16));
  a[2]=b2f((u16)(r.y & 0xffff)); a[3]=b2f((u16)(r.y >> 16));
  a[4]=b2f((u16)(r.z & 0xffff)); a[5]=b2f((u16)(r.z >> 16));
  a[6]=b2f((u16)(r.w & 0xffff)); a[7]=b2f((u16)(r.w >> 16));
}

// ---------------- setup: CSR of incoming valid edges ----------------
__global__ void k_setup(const int* __restrict__ ei, int* __restrict__ coff,
                        int* __restrict__ csrc, float* __restrict__ inv) {
  if (threadIdx.x != 0 || blockIdx.x != 0) return;
  int cnt[NS], cur[NS];
  for (int i = 0; i < NS; ++i) cnt[i] = 0;
  const int* src = ei; const int* dst = ei + NE;
  for (int e = 0; e < NE; ++e) if (src[e] != dst[e]) cnt[dst[e]]++;
  int acc = 0;
  for (int i = 0; i < NS; ++i) {
    coff[i] = acc; cur[i] = acc; acc += cnt[i];
    inv[i] = 1.0f / (float)(cnt[i] + 1);
  }
  coff[NS] = acc;
  for (int e = 0; e < NE; ++e) if (src[e] != dst[e]) csrc[cur[dst[e]]++] = src[e];
}

// ---------------- weight transpose + bf16 cast: Wt[n][k] = bf16(W[k][n]) ----------------
__global__ void k_wt(const float* __restrict__ W, u16* __restrict__ Wt, int K, int N) {
  __shared__ float t[32][33];
  int nk = K / 32;
  int bk = blockIdx.x % nk, bn = blockIdx.x / nk;
  int r = threadIdx.x >> 3, c4 = (threadIdx.x & 7) * 4;
  float4 v = *(const float4*)&W[(size_t)(bk * 32 + r) * N + bn * 32 + c4];
  t[r][c4] = v.x; t[r][c4+1] = v.y; t[r][c4+2] = v.z; t[r][c4+3] = v.w;
  __syncthreads();
  ushort4 o;
  o.x = f2b(t[c4+0][r]); o.y = f2b(t[c4+1][r]);
  o.z = f2b(t[c4+2][r]); o.w = f2b(t[c4+3][r]);
  *(ushort4*)&Wt[(size_t)(bn * 32 + r) * K + bk * 32 + c4] = o;
}

// ---------------- gather ----------------
__global__ void k_gather(const float* __restrict__ x, const int* __restrict__ nid,
                         u16* __restrict__ xt, int nrows) {
  int row = blockIdx.x * 256 + threadIdx.x;
  if (row >= nrows) return;
  int b = row / NS, i = row - b * NS;
  const float* p = x + ((size_t)b * N_TOT + nid[i]) * IN_CH;
  float4 v0 = *(const float4*)p;
  float4 v1 = *(const float4*)(p + 4);
  ushort4 o0, o1;
  o0.x = f2b(v0.x); o0.y = f2b(v0.y); o0.z = f2b(v0.z); o0.w = f2b(v0.w);
  o1.x = f2b(v1.x); o1.y = f2b(v1.y); o1.z = f2b(v1.z); o1.w = f2b(v1.w);
  ushort4* q = (ushort4*)(xt + (size_t)row * IN_CH);
  q[0] = o0; q[1] = o1;
}

// ---------------- aggregation ----------------
template<int C>
__global__ void k_aggr(const u16* __restrict__ h, u16* __restrict__ ag,
                       const int* __restrict__ coff, const int* __restrict__ csrc,
                       const float* __restrict__ inv) {
  __shared__ u16 sh[NS * C];
  __shared__ int soff[NS + 1];
  __shared__ int ssrc[NE];
  __shared__ float sinv[NS];
  const int b = blockIdx.x, t = threadIdx.x;
  const ushort4* hb4 = (const ushort4*)(h + (size_t)b * NS * C);
  ushort4* sh4 = (ushort4*)sh;
  for (int i4 = t; i4 < NS * C / 4; i4 += 256) sh4[i4] = hb4[i4];
  for (int i = t; i < NS + 1; i += 256) soff[i] = coff[i];
  for (int i = t; i < NE; i += 256) ssrc[i] = csrc[i];
  for (int i = t; i < NS; i += 256) sinv[i] = inv[i];
  __syncthreads();
  ushort4* ab4 = (ushort4*)(ag + (size_t)b * NS * C);
  for (int i4 = t; i4 < NS * C / 4; i4 += 256) {
    int i = i4 / (C / 4);
    int c0 = (i4 - i * (C / 4)) * 4;
    ushort4 sv = sh4[i4];
    float s0 = b2f(sv.x), s1 = b2f(sv.y), s2 = b2f(sv.z), s3 = b2f(sv.w);
    int e0 = soff[i], e1 = soff[i + 1];
    for (int e = e0; e < e1; ++e) {
      ushort4 nv = *(const ushort4*)&sh[ssrc[e] * C + c0];
      s0 += b2f(nv.x); s1 += b2f(nv.y); s2 += b2f(nv.z); s3 += b2f(nv.w);
    }
    float iv = sinv[i];
    ushort4 o; o.x = f2b(s0 * iv); o.y = f2b(s1 * iv); o.z = f2b(s2 * iv); o.w = f2b(s3 * iv);
    ab4[i4] = o;
  }
}

// ---------------- row L2-norm + relu ----------------
template<int C>
__global__ void k_normrelu(u16* __restrict__ h) {
  const int row = blockIdx.x * 4 + (threadIdx.x >> 6);
  const int lane = threadIdx.x & 63;
  constexpr int PER = C / 64;
  u16* hr = h + (size_t)row * C;
  float v[PER];
  if constexpr (PER == 1) {
    v[0] = b2f(hr[lane]);
  } else if constexpr (PER == 4) {
    ushort4 r = *(const ushort4*)(hr + lane * 4);
    v[0]=b2f(r.x); v[1]=b2f(r.y); v[2]=b2f(r.z); v[3]=b2f(r.w);
  } else {
    uint4 r = *(const uint4*)(hr + lane * 8);
    unpack8(r, v);
  }
  float ss = 0.f;
  #pragma unroll
  for (int j = 0; j < PER; ++j) ss += v[j] * v[j];
  #pragma unroll
  for (int d = 1; d < 64; d <<= 1) ss += __shfl_xor(ss, d);
  float rn = 1.0f / fmaxf(sqrtf(ss), 1e-12f);
  #pragma unroll
  for (int j = 0; j < PER; ++j) v[j] = fmaxf(v[j] * rn, 0.f);
  if constexpr (PER == 1) {
    hr[lane] = f2b(v[0]);
  } else if constexpr (PER == 4) {
    ushort4 o; o.x=f2b(v[0]); o.y=f2b(v[1]); o.z=f2b(v[2]); o.w=f2b(v[3]);
    *(ushort4*)(hr + lane * 4) = o;
  } else {
    ushort4 o0, o1;
    o0.x=f2b(v[0]); o0.y=f2b(v[1]); o0.z=f2b(v[2]); o0.w=f2b(v[3]);
    o1.x=f2b(v[4]); o1.y=f2b(v[5]); o1.z=f2b(v[6]); o1.w=f2b(v[7]);
    ushort4* q = (ushort4*)(hr + lane * 8); q[0]=o0; q[1]=o1;
  }
}

// ---------------- MFMA GEMM: C[M,N] = [A|A2](bf16) @ Bt^T(bf16) (+bias) ----------------
// 128x128 tile, BK=32, 4 waves (2x2) each 64x64 via 4x4 16x16x32 fragments.
// grid: (M/128, N/128, splits). Bt is [N][K] row-major bf16.
// OBF16: bf16 out with bias. else: f32 partial to Cv + split*Mtot*N (no bias).
template<bool CONCAT, bool OBF16>
__global__ __launch_bounds__(256)
void k_mfma(const u16* __restrict__ A, const u16* __restrict__ A2,
            const u16* __restrict__ Bt, const float* __restrict__ bias,
            void* __restrict__ Cv, int N, int K, int CIN,
            int kPerSplit, int Mtot) {
  __shared__ u16 As[2][128 * 32];
  __shared__ u16 Bs[2][128 * 32];
  const int t = threadIdx.x;
  const int row0 = blockIdx.x * 128;
  const int col0 = blockIdx.y * 128;
  const int split = blockIdx.z;
  const int kbeg = split * kPerSplit;
  const int w = t >> 6, l = t & 63;
  const int wm = w >> 1, wn = w & 1;
  const int lr = l & 15, lk = (l >> 4) * 8;
  const int s_r = t >> 2;            // staging row 0..63 (chunk adds +64)
  const int s_c = (t & 3) * 8;       // staging col (elements)

  f32x4_t acc[4][4];
  #pragma unroll
  for (int i = 0; i < 4; ++i)
    #pragma unroll
    for (int j = 0; j < 4; ++j) acc[i][j] = (f32x4_t){0.f, 0.f, 0.f, 0.f};

  auto stage = [&](int buf, int k0) {
    const u16* abase; int astride, koff;
    if constexpr (CONCAT) {
      astride = CIN;
      if (k0 < CIN) { abase = A; koff = k0; } else { abase = A2; koff = k0 - CIN; }
    } else { abase = A; astride = K; koff = k0; }
    const u16* ga0 = abase + (size_t)(row0 + s_r) * astride + koff + s_c;
    const u16* ga1 = abase + (size_t)(row0 + 64 + s_r) * astride + koff + s_c;
    u16* la = &As[buf][w * 512];
    __builtin_amdgcn_global_load_lds(AS1C(ga0), AS3(la), 16, 0, 0);
    __builtin_amdgcn_global_load_lds(AS1C(ga1), AS3(la + 2048), 16, 0, 0);
    const u16* gb0 = Bt + (size_t)(col0 + s_r) * K + k0 + s_c;
    const u16* gb1 = Bt + (size_t)(col0 + 64 + s_r) * K + k0 + s_c;
    u16* lb = &Bs[buf][w * 512];
    __builtin_amdgcn_global_load_lds(AS1C(gb0), AS3(lb), 16, 0, 0);
    __builtin_amdgcn_global_load_lds(AS1C(gb1), AS3(lb + 2048), 16, 0, 0);
  };

  const int nsteps = kPerSplit / 32;
  stage(0, kbeg);
  __syncthreads();
  for (int s = 0; s < nsteps; ++s) {
    const int buf = s & 1;
    if (s + 1 < nsteps) stage(buf ^ 1, kbeg + (s + 1) * 32);
    bf16x8_t af[4], bfr[4];
    #pragma unroll
    for (int f = 0; f < 4; ++f) {
      af[f]  = *(const bf16x8_t*)&As[buf][(wm * 64 + f * 16 + lr) * 32 + lk];
      bfr[f] = *(const bf16x8_t*)&Bs[buf][(wn * 64 + f * 16 + lr) * 32 + lk];
    }
    #pragma unroll
    for (int i = 0; i < 4; ++i)
      #pragma unroll
      for (int j = 0; j < 4; ++j)
        acc[i][j] = __builtin_amdgcn_mfma_f32_16x16x32_bf16(af[i], bfr[j], acc[i][j], 0, 0, 0);
    __syncthreads();
  }

  // epilogue: C/D layout col=lane&15, row=(lane>>4)*4+reg
  const int rbase = (l >> 4) * 4;
  #pragma unroll
  for (int j = 0; j < 4; ++j) {
    const int c = col0 + wn * 64 + j * 16 + lr;
    float bv = 0.f;
    if constexpr (OBF16) bv = bias[c];
    #pragma unroll
    for (int i = 0; i < 4; ++i) {
      const int r0 = row0 + wm * 64 + i * 16 + rbase;
      if constexpr (OBF16) {
        u16* C = (u16*)Cv;
        #pragma unroll
        for (int r = 0; r < 4; ++r)
          C[(size_t)(r0 + r) * N + c] = f2b(acc[i][j][r] + bv);
      } else {
        float* P = (float*)Cv + (size_t)split * Mtot * N;
        #pragma unroll
        for (int r = 0; r < 4; ++r)
          P[(size_t)(r0 + r) * N + c] = acc[i][j][r];
      }
    }
  }
}

// ---------------- split-K reduce: y = relu(sum_s P[s] + bias), N=1024 ----------------
__global__ void k_red4(const float* __restrict__ P, const float* __restrict__ bias,
                       float* __restrict__ y, int MN) {
  int i = blockIdx.x * 256 + threadIdx.x;
  if (i * 4 >= MN) return;
  const float4* p = (const float4*)P;
  int stride = MN / 4;
  float4 a = p[i], b = p[i + stride], c = p[i + 2 * stride], d = p[i + 3 * stride];
  float4 bv = *(const float4*)&bias[(i * 4) & 1023];
  float4 o;
  o.x = fmaxf(a.x + b.x + c.x + d.x + bv.x, 0.f);
  o.y = fmaxf(a.y + b.y + c.y + d.y + bv.y, 0.f);
  o.z = fmaxf(a.z + b.z + c.z + d.z + bv.z, 0.f);
  o.w = fmaxf(a.w + b.w + c.w + d.w + bv.w, 0.f);
  ((float4*)y)[i] = o;
}

// ---------------- VALU tiled GEMM (conv1, L2) ----------------
template<bool ABF16, int CIN, bool RELU, bool OBF16, bool NGUARD>
__global__ __launch_bounds__(256)
void k_gemm(const void* __restrict__ Av, const void* __restrict__ A2v,
            const float* __restrict__ W, const float* __restrict__ bias,
            void* __restrict__ Cv, int N, int K, int ntiles) {
  __shared__ float As[128][20];
  __shared__ float Bs[16][64];
  const int t = threadIdx.x;
  const int bx = blockIdx.x;
  const int mt = bx / ntiles, nt = bx - mt * ntiles;
  const int row0 = mt * 128, col0 = nt * 64;
  const int tr = t >> 4, tc = t & 15;
  const int arow = t >> 1, acol = (t & 1) * 8;
  const int brow = t >> 4, bcol = (t & 15) * 4;

  float acc[8][4];
  #pragma unroll
  for (int r = 0; r < 8; ++r)
    #pragma unroll
    for (int c = 0; c < 4; ++c) acc[r][c] = 0.f;

  for (int k0 = 0; k0 < K; k0 += 16) {
    {
      int gk = k0 + acol;
      const void* base; int koff, lda;
      if constexpr (CIN > 0) {
        lda = CIN;
        if (gk < CIN) { base = Av; koff = gk; } else { base = A2v; koff = gk - CIN; }
      } else { base = Av; koff = gk; lda = K; }
      float av[8];
      if constexpr (ABF16) {
        const u16* p = (const u16*)base + (size_t)(row0 + arow) * lda + koff;
        uint4 raw = *(const uint4*)p;
        unpack8(raw, av);
      } else {
        const float* p = (const float*)base + (size_t)(row0 + arow) * lda + koff;
        float4 u = *(const float4*)p; float4 w2 = *(const float4*)(p + 4);
        av[0]=u.x; av[1]=u.y; av[2]=u.z; av[3]=u.w;
        av[4]=w2.x; av[5]=w2.y; av[6]=w2.z; av[7]=w2.w;
      }
      *(float4*)&As[arow][acol]     = make_float4(av[0],av[1],av[2],av[3]);
      *(float4*)&As[arow][acol + 4] = make_float4(av[4],av[5],av[6],av[7]);
    }
    {
      int gk = k0 + brow, gn = col0 + bcol;
      const float* wp = W + (size_t)gk * N + gn;
      if constexpr (!NGUARD) {
        *(float4*)&Bs[brow][bcol] = *(const float4*)wp;
      } else {
        #pragma unroll
        for (int j = 0; j < 4; ++j) Bs[brow][bcol + j] = (gn + j < N) ? wp[j] : 0.f;
      }
    }
    __syncthreads();
    #pragma unroll
    for (int kk = 0; kk < 16; kk += 4) {
      float4 b0 = *(float4*)&Bs[kk + 0][tc * 4];
      float4 b1 = *(float4*)&Bs[kk + 1][tc * 4];
      float4 b2 = *(float4*)&Bs[kk + 2][tc * 4];
      float4 b3 = *(float4*)&Bs[kk + 3][tc * 4];
      #pragma unroll
      for (int r = 0; r < 8; ++r) {
        float4 a = *(float4*)&As[tr + 16 * r][kk];
        acc[r][0] += a.x*b0.x; acc[r][1] += a.x*b0.y; acc[r][2] += a.x*b0.z; acc[r][3] += a.x*b0.w;
        acc[r][0] += a.y*b1.x; acc[r][1] += a.y*b1.y; acc[r][2] += a.y*b1.z; acc[r][3] += a.y*b1.w;
        acc[r][0] += a.z*b2.x; acc[r][1] += a.z*b2.y; acc[r][2] += a.z*b2.z; acc[r][3] += a.z*b2.w;
        acc[r][0] += a.w*b3.x; acc[r][1] += a.w*b3.y; acc[r][2] += a.w*b3.z; acc[r][3] += a.w*b3.w;
      }
    }
    __syncthreads();
  }
  float bv[4];
  #pragma unroll
  for (int c = 0; c < 4; ++c) {
    int gn = col0 + tc * 4 + c;
    bv[c] = (!NGUARD || gn < N) ? bias[gn] : 0.f;
  }
  #pragma unroll
  for (int r = 0; r < 8; ++r) {
    int gr = row0 + tr + 16 * r;
    float v[4];
    #pragma unroll
    for (int c = 0; c < 4; ++c) {
      v[c] = acc[r][c] + bv[c];
      if constexpr (RELU) v[c] = fmaxf(v[c], 0.f);
    }
    if constexpr (OBF16) {
      u16* cp = (u16*)Cv + (size_t)gr * N + col0 + tc * 4;
      ushort4 o; o.x=f2b(v[0]); o.y=f2b(v[1]); o.z=f2b(v[2]); o.w=f2b(v[3]);
      *(ushort4*)cp = o;
    } else {
      float* cp = (float*)Cv + (size_t)gr * N + col0 + tc * 4;
      if constexpr (!NGUARD) {
        *(float4*)cp = make_float4(v[0], v[1], v[2], v[3]);
      } else {
        #pragma unroll
        for (int c = 0; c < 4; ++c)
          if (col0 + tc * 4 + c < N) cp[c] = v[c];
      }
    }
  }
}

// ---------------- final 218 -> 2 ----------------
__global__ void k_l3(const float* __restrict__ y2, const float* __restrict__ w,
                     const float* __restrict__ b, float* __restrict__ out, int nrows) {
  int idx = blockIdx.x * 256 + threadIdx.x;
  if (idx >= nrows * 2) return;
  int o = idx & 1, row = idx >> 1;
  const float* yr = y2 + (size_t)row * L2_OUT;
  float s = b[o];
  for (int k = 0; k < L2_OUT; ++k) s += yr[k] * w[k * 2 + o];
  out[idx] = s;
}

extern "C" void kernel_launch(void* const* d_in, const int* in_sizes, int n_in,
                              void* d_out, int out_size, void* d_ws, size_t ws_size,
                              hipStream_t stream) {
  const float* x   = (const float*)d_in[0];
  const int*   nid = (const int*)d_in[1];
  const int*   ei  = (const int*)d_in[2];
  const float* W1  = (const float*)d_in[3];  const float* b1 = (const float*)d_in[4];
  const float* W2  = (const float*)d_in[5];  const float* b2 = (const float*)d_in[6];
  const float* W3  = (const float*)d_in[7];  const float* b3 = (const float*)d_in[8];
  const float* L1w = (const float*)d_in[9];  const float* L1b = (const float*)d_in[10];
  const float* L2w = (const float*)d_in[11]; const float* L2b = (const float*)d_in[12];
  const float* L3w = (const float*)d_in[13]; const float* L3b = (const float*)d_in[14];
  float* out = (float*)d_out;

  char* ws = (char*)d_ws;
  // ---- fixed region: transposed bf16 weights + CSR meta ----
  u16* Wt2  = (u16*)ws;                         //  256*128*2  =     65,536
  u16* Wt3  = (u16*)(ws + 65536);               //  512*512*2  =    524,288
  u16* WtL1 = (u16*)(ws + 65536 + 524288);      // 1024*39424*2=  80,740,352
  size_t WOFF = 65536 + 524288 + 80740352;      // 81,330,176
  int*   coff = (int*)(ws + WOFF);
  int*   csrc = coff + 80;
  float* invc = (float*)(csrc + 400);
  size_t CHUNK0 = WOFF + 4096;

  // ---- adaptive batch-chunk: per-chunk 3-region overlay = Bc*157,696 B ----
  int Bc = 4096;
  while (Bc > 128 && CHUNK0 + (size_t)Bc * 157696 > ws_size) Bc >>= 1;

  char* r1 = ws + CHUNK0;                       // h2 -> y1 + P(splitK)
  char* r2 = r1 + (size_t)Bc * 39424;           // h1 -> ag2 -> y2
  char* r3 = r2 + (size_t)Bc * 39424;           // xt0+ag0 -> ag1 -> h3

  k_setup<<<1, 64, 0, stream>>>(ei, coff, csrc, invc);
  k_wt<<<(128/32)*(256/32),   256, 0, stream>>>(W2,  Wt2,  128,   256);
  k_wt<<<(512/32)*(512/32),   256, 0, stream>>>(W3,  Wt3,  512,   512);
  k_wt<<<(39424/32)*(1024/32),256, 0, stream>>>(L1w, WtL1, 39424, 1024);

  for (int b0 = 0; b0 < B_SZ; b0 += Bc) {
    const int nb = Bc;
    const int rows = nb * NS;                   // multiple of 128
    const int mt = rows / 128;
    u16* xt0 = (u16*)r3;
    u16* ag0 = (u16*)(r3 + (size_t)nb * 1232);
    u16* h1  = (u16*)r2;
    u16* ag1 = (u16*)r3;
    u16* h2  = (u16*)r1;
    u16* ag2 = (u16*)r2;
    u16* h3  = (u16*)r3;
    float* y1c = (float*)r1;
    float* Pc  = (float*)(r1 + (size_t)nb * 4096);   // 4 partials, nb*16384 B
    float* y2c = (float*)r2;
    const float* xb = x + (size_t)b0 * N_TOT * IN_CH;

    k_gather<<<(rows + 255) / 256, 256, 0, stream>>>(xb, nid, xt0, rows);

    // conv1: 8 -> 64 (VALU, K=16)
    k_aggr<8><<<nb, 256, 0, stream>>>(xt0, ag0, coff, csrc, invc);
    k_gemm<true, 8, false, true, false><<<mt, 256, 0, stream>>>(
        xt0, ag0, W1, b1, h1, 64, 16, 1);
    k_normrelu<64><<<rows / 4, 256, 0, stream>>>(h1);

    // conv2: 64 -> 256 (MFMA)
    k_aggr<64><<<nb, 256, 0, stream>>>(h1, ag1, coff, csrc, invc);
    k_mfma<true, true><<<dim3(mt, 2, 1), 256, 0, stream>>>(
        h1, ag1, Wt2, b2, h2, 256, 128, 64, 128, rows);
    k_normrelu<256><<<rows / 4, 256, 0, stream>>>(h2);

    // conv3: 256 -> 512 (MFMA)
    k_aggr<256><<<nb, 256, 0, stream>>>(h2, ag2, coff, csrc, invc);
    k_mfma<true, true><<<dim3(mt, 4, 1), 256, 0, stream>>>(
        h2, ag2, Wt3, b3, h3, 512, 512, 256, 512, rows);
    k_normrelu<512><<<rows / 4, 256, 0, stream>>>(h3);

    // L1: (nb x 39424) @ Wt^T -> partials (split-K = 4), then reduce+bias+relu
    k_mfma<false, false><<<dim3(nb / 128, 8, 4), 256, 0, stream>>>(
        h3, nullptr, WtL1, nullptr, Pc, 1024, 39424, 0, 9856, nb);
    k_red4<<<nb, 256, 0, stream>>>(Pc, L1b, y1c, nb * 1024);

    // L2: (nb x 1024) @ (1024 x 218), relu (VALU, N guarded)
    k_gemm<false, 0, true, false, true><<<(nb / 128) * 4, 256, 0, stream>>>(
        y1c, nullptr, L2w, L2b, y2c, 218, 1024, 4);
    // L3
    k_l3<<<(nb * 2 + 255) / 256, 256, 0, stream>>>(y2c, L3w, L3b, out + (size_t)b0 * 2, nb);
  }
}